// Round 15
// baseline (215.713 us; speedup 1.0000x reference)
//
#include <hip/hip_runtime.h>

// Green-Ampt infiltration scan. B=16384 rows x T=2048 steps. TWO PASS:
//   pass1: per-row serial chain, checkpoints F at 16 segment boundaries (d_ws)
//   pass2: persistent blocks; producer wave recomputes 2 rows x 16 segments
//          from checkpoints into double-buffered LDS; 3 consumer waves flush
//          one output stream each as FULL-8KB-ROW CONTIGUOUS nontemporal runs.
//
// Evidence ledger:
//  R1-R9: cached-store regime capped at ~3 TB/s regardless of concurrency/
//         run-length/bank-rotation/L2-set phase (cache path was the wall).
//  R10: wave-contiguous nt stores -> 132us. Cache path confirmed as wall.
//  R11/R12: +dedicated store waves -> 120 -> 106us (~3.8 TB/s writes).
//  R13 (12 waves) 116us, R14 (flag handshake) 112.6us -> R12 local optimum.
// Untested-in-nt-regime axis: contiguity. R12 runs are 256B with 8KB jumps
// (page-activate per 256B); fill (6.9 TB/s) sweeps linearly. R15 makes every
// flush an 8KB contiguous run.

#define GA_MIN_INF 0.1f
#define GA_EPS 1e-6f

typedef float f4 __attribute__((ext_vector_type(4)));

constexpr int SEGS  = 16;            // checkpoint segments (seglen = 128)
constexpr int PITCH = 132;           // floats per segment chunk (128 + pad)
constexpr int RPI   = 2;             // rows per pass2 iteration
constexpr int CHUNK = SEGS * PITCH;  // 2112 floats per row

__device__ __forceinline__ void ga_step(float& F, float Kv, float kpd,
                                        float pv, float& fi, float& ro) {
  float rF   = __builtin_amdgcn_rcpf(fmaxf(F, GA_EPS));
  float fcap = fmaxf(Kv + kpd * rF, GA_MIN_INF);
  float fact = fminf(pv, fcap);
  ro = fmaxf(pv - fact, 0.0f);
  F += fact;
  fi = fact;
}

// ---------------- Pass 1: state-only scan, checkpoint every T/SEGS steps ----
__global__ __launch_bounds__(64, 1) void ga_pass1(
    const float* __restrict__ precip, const float* __restrict__ K,
    const float* __restrict__ psi, const float* __restrict__ dtheta,
    float* __restrict__ cp, int B, int T) {
  const int b = blockIdx.x * 64 + threadIdx.x;
  if (b >= B) return;
  const float Kv  = K[b];
  const float kpd = Kv * (psi[b] * dtheta[b]);
  const f4* __restrict__ pr = reinterpret_cast<const f4*>(precip + (size_t)b * T);

  const int nbat = T / 32;                   // 64
  const int bats_per_seg = (T / SEGS) / 32;  // 4

  float F = 0.0f;
  f4 buf[8], nxt[8];
#pragma unroll
  for (int i = 0; i < 8; ++i) buf[i] = pr[i];

  for (int bat = 0; bat < nbat; ++bat) {
    if ((bat % bats_per_seg) == 0) cp[(size_t)(bat / bats_per_seg) * B + b] = F;
    if (bat + 1 < nbat) {
#pragma unroll
      for (int i = 0; i < 8; ++i) nxt[i] = pr[(bat + 1) * 8 + i];
    }
#pragma unroll
    for (int i = 0; i < 8; ++i) {
      const f4 p = buf[i];
#pragma unroll
      for (int j = 0; j < 4; ++j) {
        float fi_, ro_;
        ga_step(F, Kv, kpd, p[j], fi_, ro_);
      }
    }
#pragma unroll
    for (int i = 0; i < 8; ++i) buf[i] = nxt[i];
  }
}

// ------- Pass 2: persistent producer/consumer, 8KB-contiguous nt flush ------
__global__ __launch_bounds__(256, 1) void ga_pass2(
    const float* __restrict__ precip, const float* __restrict__ K,
    const float* __restrict__ psi, const float* __restrict__ dtheta,
    const float* __restrict__ cp, float* __restrict__ out, int B, int T) {
  __shared__ float sb[2][3][RPI * CHUNK];   // 101.4 KB

  const int tid  = threadIdx.x;
  const int wid  = tid >> 6;
  const int lane = tid & 63;
  const int rowbase = blockIdx.x * 64;      // this block owns 64 rows

  const size_t BT = (size_t)B * (size_t)T;
  const int seglen = T / SEGS;              // 128
  const int niter  = 64 / RPI;              // 32

  if (wid == 0) {
    // -------- producer: 32 active lanes = (row 0/1, seg 0..15) -------------
    const int row = lane & 1;
    const int seg = lane >> 1;
    const bool active = lane < 32;

    for (int it = 0; it < niter; ++it) {
      const int pb = it & 1;
      if (active) {
        const int grow = rowbase + it * RPI + row;
        const float Kv  = K[grow];
        const float kpd = Kv * (psi[grow] * dtheta[grow]);
        float F = cp[(size_t)seg * B + grow];
        const f4* __restrict__ pr =
            reinterpret_cast<const f4*>(precip + (size_t)grow * T + seg * seglen);
        float* const L0 = &sb[pb][0][row * CHUNK + seg * PITCH];
        float* const L1 = &sb[pb][1][row * CHUNK + seg * PITCH];
        float* const L2 = &sb[pb][2][row * CHUNK + seg * PITCH];

        f4 buf[8], nxt[8];
#pragma unroll
        for (int i = 0; i < 8; ++i) buf[i] = pr[i];
#pragma unroll
        for (int q = 0; q < 4; ++q) {        // 4 x 32 steps = 128
          if (q < 3) {
#pragma unroll
            for (int i = 0; i < 8; ++i) nxt[i] = pr[(q + 1) * 8 + i];
          }
#pragma unroll
          for (int i = 0; i < 8; ++i) {
            const f4 p = buf[i];
            f4 a, r, c;
#pragma unroll
            for (int j = 0; j < 4; ++j) {
              float fi_, ro_;
              ga_step(F, Kv, kpd, p[j], fi_, ro_);
              a[j] = fi_; r[j] = ro_; c[j] = F;
            }
            const int t0 = q * 32 + i * 4;
            *reinterpret_cast<f4*>(L0 + t0) = a;
            *reinterpret_cast<f4*>(L1 + t0) = r;
            *reinterpret_cast<f4*>(L2 + t0) = c;
          }
#pragma unroll
          for (int i = 0; i < 8; ++i) buf[i] = nxt[i];
        }
      }
      asm volatile("s_waitcnt lgkmcnt(0)" ::: "memory");
      __builtin_amdgcn_s_barrier();
    }
  } else {
    // -------- consumers: one wave per stream; 8KB contiguous nt runs -------
    const int s = wid - 1;
    float* const dstS = out + (size_t)s * BT;
    const int segl = lane >> 5;              // 0/1: segment parity within 1KB
    const int off  = (lane & 31) * 4;        // float offset within segment

    for (int it = 0; it < niter; ++it) {
      if (it > 0) {
        const float* const src = &sb[(it - 1) & 1][s][0];
#pragma unroll
        for (int r = 0; r < RPI; ++r) {
          const int grow = rowbase + (it - 1) * RPI + r;
          float* const dst = dstS + (size_t)grow * T;
#pragma unroll
          for (int g = 0; g < 8; ++g) {      // 8 x 1KB = one 8KB row, linear
            const int idx = r * CHUNK + (g * 2 + segl) * PITCH + off;
            f4 v = *reinterpret_cast<const f4*>(&src[idx]);
            __builtin_nontemporal_store(
                v, reinterpret_cast<f4*>(dst + g * 256 + lane * 4));
          }
        }
      }
      asm volatile("s_waitcnt lgkmcnt(0)" ::: "memory");
      __builtin_amdgcn_s_barrier();
    }
    // epilogue: flush pair niter-1
    {
      const float* const src = &sb[(niter - 1) & 1][s][0];
#pragma unroll
      for (int r = 0; r < RPI; ++r) {
        const int grow = rowbase + (niter - 1) * RPI + r;
        float* const dst = dstS + (size_t)grow * T;
#pragma unroll
        for (int g = 0; g < 8; ++g) {
          const int idx = r * CHUNK + (g * 2 + segl) * PITCH + off;
          f4 v = *reinterpret_cast<const f4*>(&src[idx]);
          __builtin_nontemporal_store(
              v, reinterpret_cast<f4*>(dst + g * 256 + lane * 4));
        }
      }
    }
  }
}

// ---------------- Fallback (naive) for unexpected shapes --------------------
__global__ void ga_fallback(
    const float* __restrict__ precip, const float* __restrict__ K,
    const float* __restrict__ psi, const float* __restrict__ dtheta,
    float* __restrict__ out, int B, int T) {
  int b = blockIdx.x * blockDim.x + threadIdx.x;
  if (b >= B) return;
  const float Kv  = K[b];
  const float kpd = Kv * (psi[b] * dtheta[b]);
  const size_t BT = (size_t)B * (size_t)T;
  float F = 0.0f;
  for (int t = 0; t < T; ++t) {
    float pv = precip[(size_t)b * T + t];
    float fi_, ro_;
    ga_step(F, Kv, kpd, pv, fi_, ro_);
    out[(size_t)b * T + t] = fi_;
    out[BT + (size_t)b * T + t] = ro_;
    out[2 * BT + (size_t)b * T + t] = F;
  }
}

extern "C" void kernel_launch(void* const* d_in, const int* in_sizes, int n_in,
                              void* d_out, int out_size, void* d_ws, size_t ws_size,
                              hipStream_t stream) {
  const float* precip = (const float*)d_in[0];
  const float* K      = (const float*)d_in[1];
  const float* psi    = (const float*)d_in[2];
  const float* dtheta = (const float*)d_in[3];
  float* out = (float*)d_out;

  const int B = in_sizes[1];            // K has B elements
  const int T = in_sizes[0] / B;        // precip is B*T

  const size_t cp_bytes = (size_t)SEGS * (size_t)B * sizeof(float);
  const bool ok = (B % 64) == 0 && T == 2048;   // layout constants assume T=2048

  if (ws_size >= cp_bytes && ok) {
    float* cp = (float*)d_ws;
    ga_pass1<<<B / 64, 64, 0, stream>>>(precip, K, psi, dtheta, cp, B, T);
    ga_pass2<<<B / 64, 256, 0, stream>>>(precip, K, psi, dtheta, cp, out, B, T);
  } else {
    ga_fallback<<<(B + 63) / 64, 64, 0, stream>>>(precip, K, psi, dtheta, out, B, T);
  }
}

// Round 16
// 111.873 us; speedup vs baseline: 1.9282x; 1.9282x over previous
//
#include <hip/hip_runtime.h>

// Green-Ampt infiltration scan. B=16384 rows x T=2048 steps. Single pass,
// producer/consumer wave split + NONTEMPORAL flush stores.
//
// Evidence ledger:
//  R1-R9:  all cached-store variants pinned at ~3 TB/s (cache write path).
//  R10:    wave-contiguous nt stores -> 132us. Cache path confirmed.
//  R11/R12: dedicated store waves 3 -> 6: 120 -> 106us (~4.1 TB/s writes).
//  R13: 12 waves -> 116us (width non-monotone). R14: flag handshake -> 112.
//  R15: 2-pass contiguous-flush attempt -> 215us (producer starved; test
//       confounded, contiguity axis still open).
// R16 = R12 with ONE change: 3-deep LDS staging; consumers flush a PAIR of
// stages every other interval, so each nt store instruction covers 2 rows x
// 512B contiguous (vs 256B in R12). Clean run-length A/B in the nt regime.

#define GA_MIN_INF 0.1f
#define GA_EPS 1e-6f

typedef float f4 __attribute__((ext_vector_type(4)));

constexpr int ROWS  = 64;   // rows per block (= lanes of wave 0)
constexpr int TS    = 64;   // timesteps per stage
constexpr int PITCH = 68;   // LDS row pitch in floats (16B-aligned)
constexpr int DEPTH = 3;    // staging depth (enables pair flush)

__global__ __launch_bounds__(448, 1) void ga_pc(
    const float* __restrict__ precip, const float* __restrict__ K,
    const float* __restrict__ psi, const float* __restrict__ dtheta,
    float* __restrict__ out, int B, int T) {
  __shared__ float sb[DEPTH][3][ROWS * PITCH];  // 156.7 KB

  const int tid  = threadIdx.x;
  const int wid  = tid >> 6;
  const int lane = tid & 63;
  const int rowbase = blockIdx.x * ROWS;

  const size_t BT = (size_t)B * (size_t)T;
  const int nstage = T / TS;                 // 32 (even)
  const int nsb    = T / 32;                 // 32-step sub-batches (64)

  if (wid == 0) {
    // ---------------- producer: serial recurrence into LDS stages ----------
    const int b = rowbase + lane;
    const float Kv  = K[b];
    const float kpd = Kv * (psi[b] * dtheta[b]);
    const f4* __restrict__ pr = reinterpret_cast<const f4*>(precip + (size_t)b * T);

    float F = 0.0f;
    f4 buf[8], nxt[8];
#pragma unroll
    for (int i = 0; i < 8; ++i) buf[i] = pr[i];

    int sbc = 0;
    for (int st = 0; st < nstage; ++st) {
      const int pb = st % DEPTH;
      float* const L0 = &sb[pb][0][lane * PITCH];
      float* const L1 = &sb[pb][1][lane * PITCH];
      float* const L2 = &sb[pb][2][lane * PITCH];
#pragma unroll
      for (int q = 0; q < 2; ++q) {          // 2 x 32 steps = TS
        if (sbc + 1 < nsb) {
#pragma unroll
          for (int i = 0; i < 8; ++i) nxt[i] = pr[(sbc + 1) * 8 + i];
        }
#pragma unroll
        for (int i = 0; i < 8; ++i) {
          const f4 p = buf[i];
          f4 a, r, c;
#pragma unroll
          for (int j = 0; j < 4; ++j) {
            float rF   = __builtin_amdgcn_rcpf(fmaxf(F, GA_EPS));
            float fcap = fmaxf(Kv + kpd * rF, GA_MIN_INF);
            float fact = fminf(p[j], fcap);
            r[j] = fmaxf(p[j] - fact, 0.0f);
            F += fact;
            a[j] = fact;
            c[j] = F;
          }
          const int t0 = q * 32 + i * 4;
          *reinterpret_cast<f4*>(L0 + t0) = a;
          *reinterpret_cast<f4*>(L1 + t0) = r;
          *reinterpret_cast<f4*>(L2 + t0) = c;
        }
#pragma unroll
        for (int i = 0; i < 8; ++i) buf[i] = nxt[i];
        ++sbc;
      }
      // LDS writes visible before consumers cross the barrier; no vmcnt drain.
      asm volatile("s_waitcnt lgkmcnt(0)" ::: "memory");
      __builtin_amdgcn_s_barrier();
    }
  } else {
    // ---- consumers: 2 waves/stream; flush PAIRS of stages, 512B runs ------
    const int s = (wid - 1) % 3;             // stream
    const int h = (wid - 1) / 3;             // row half: rows h*32 .. h*32+31
    float* const dst = out + (size_t)s * BT;
    const int fr  = lane >> 5;               // 0..1 : row within pair
    const int l32 = lane & 31;
    const int fc  = l32 * 4;                 // float col 0..124 within 128-col pair

    // pair flush: one instruction covers rows {2g+,} x 512B contiguous
    auto flush_pair = [&](int p0) {
      const float* const sA = &sb[p0 % DEPTH][s][0];
      const float* const sB = &sb[(p0 + 1) % DEPTH][s][0];
      const int tb = p0 * TS;
#pragma unroll
      for (int g = 0; g < 16; ++g) {
        const int r = h * 32 + g * 2 + fr;
        // cols 0..63 live in slot p0, cols 64..127 in slot p0+1
        const float* src = (l32 < 16) ? &sA[r * PITCH + fc]
                                      : &sB[r * PITCH + fc - TS];
        f4 v = *reinterpret_cast<const f4*>(src);
        __builtin_nontemporal_store(
            v, reinterpret_cast<f4*>(dst + (size_t)(rowbase + r) * T + tb + fc));
      }
    };

    for (int st = 0; st < nstage; ++st) {
      if (st >= 2 && (st & 1) == 0) flush_pair(st - 2);
      asm volatile("s_waitcnt lgkmcnt(0)" ::: "memory");
      __builtin_amdgcn_s_barrier();
    }
    // epilogue: last pair (producer done; no barrier needed)
    flush_pair(nstage - 2);
  }
}

// Fallback for shapes not divisible by the tiling (not hit for 16384x2048).
__global__ void ga_fallback(
    const float* __restrict__ precip, const float* __restrict__ K,
    const float* __restrict__ psi, const float* __restrict__ dtheta,
    float* __restrict__ out, int B, int T) {
  int b = blockIdx.x * blockDim.x + threadIdx.x;
  if (b >= B) return;
  const float Kv  = K[b];
  const float kpd = Kv * (psi[b] * dtheta[b]);
  const size_t BT = (size_t)B * (size_t)T;
  float F = 0.0f;
  for (int t = 0; t < T; ++t) {
    float pv   = precip[(size_t)b * T + t];
    float rF   = __builtin_amdgcn_rcpf(fmaxf(F, GA_EPS));
    float fcap = fmaxf(Kv + kpd * rF, GA_MIN_INF);
    float fact = fminf(pv, fcap);
    float ro   = fmaxf(pv - fact, 0.0f);
    F += fact;
    out[(size_t)b * T + t] = fact;
    out[BT + (size_t)b * T + t] = ro;
    out[2 * BT + (size_t)b * T + t] = F;
  }
}

extern "C" void kernel_launch(void* const* d_in, const int* in_sizes, int n_in,
                              void* d_out, int out_size, void* d_ws, size_t ws_size,
                              hipStream_t stream) {
  const float* precip = (const float*)d_in[0];
  const float* K      = (const float*)d_in[1];
  const float* psi    = (const float*)d_in[2];
  const float* dtheta = (const float*)d_in[3];
  float* out = (float*)d_out;

  const int B = in_sizes[1];            // K has B elements
  const int T = in_sizes[0] / B;        // precip is B*T

  if ((B % ROWS) == 0 && (T % (2 * TS)) == 0 && ((T / 32) % 2) == 0) {
    ga_pc<<<B / ROWS, 448, 0, stream>>>(precip, K, psi, dtheta, out, B, T);
  } else {
    ga_fallback<<<(B + 63) / 64, 64, 0, stream>>>(precip, K, psi, dtheta, out, B, T);
  }
}

// Round 18
// 97.442 us; speedup vs baseline: 2.2138x; 1.1481x over previous
//
#include <hip/hip_runtime.h>

// Green-Ampt infiltration scan. B=16384 rows x T=2048 steps. Single pass,
// producer/consumer wave split + NONTEMPORAL flush stores, 2 blocks/CU.
//
// Evidence ledger:
//  R1-R9:  cached-store regime pinned at ~3 TB/s (cache write path = wall).
//  R10:    wave-contiguous nt stores -> 132us. Cache path confirmed.
//  R11/R12: dedicated store waves 3 -> 6: 120 -> 106us (~4.4 TB/s HBM).
//  R13: 12 waves 116us. R14: flag handshake 112.6us. R16: 512B runs 111.9us.
//  R15: 2-pass contiguous 215us (producer starved).
//  R17: 2-blocks/CU attempt FAILED (inf): s_barrier inside divergent branch
//       -> wave0 executed ~2x barriers -> desync. Bug, not theory.
// R18 = R17 with barrier hoisted to uniform control flow: compute guarded by
// (lane < ROWS), reconverge, then one lgkmcnt+s_barrier per stage per wave.
// Theory unchanged: block A's drain overlaps block B's compute, no shared
// barrier chain -> smoother store stream than 1 big block/CU.

#define GA_MIN_INF 0.1f
#define GA_EPS 1e-6f

typedef float f4 __attribute__((ext_vector_type(4)));

constexpr int ROWS  = 32;   // rows per block
constexpr int TS    = 64;   // timesteps per stage (256B per row per stream)
constexpr int PITCH = 68;   // LDS row pitch in floats (16B-aligned)

__global__ __launch_bounds__(448, 1) void ga_pc(
    const float* __restrict__ precip, const float* __restrict__ K,
    const float* __restrict__ psi, const float* __restrict__ dtheta,
    float* __restrict__ out, int B, int T) {
  __shared__ float sb[2][3][ROWS * PITCH];   // 52.2 KB -> 2 blocks/CU

  const int tid  = threadIdx.x;
  const int wid  = tid >> 6;
  const int lane = tid & 63;
  const int rowbase = blockIdx.x * ROWS;

  const size_t BT = (size_t)B * (size_t)T;
  const int nstage = T / TS;                 // 32
  const int nsb    = T / 32;                 // 32-step sub-batches (64)

  if (wid == 0) {
    // ------------- producer: 32 active lanes, serial recurrence ------------
    const bool active = lane < ROWS;
    const int b = rowbase + (active ? lane : 0);   // clamped; idle lanes unused
    const float Kv  = K[b];
    const float kpd = Kv * (psi[b] * dtheta[b]);
    const f4* __restrict__ pr = reinterpret_cast<const f4*>(precip + (size_t)b * T);

    float F = 0.0f;
    f4 buf[8], nxt[8];
    if (active) {
#pragma unroll
      for (int i = 0; i < 8; ++i) buf[i] = pr[i];
    }

    int sbc = 0;
    for (int st = 0; st < nstage; ++st) {
      const int pb = st & 1;
      if (active) {
        float* const L0 = &sb[pb][0][lane * PITCH];
        float* const L1 = &sb[pb][1][lane * PITCH];
        float* const L2 = &sb[pb][2][lane * PITCH];
#pragma unroll
        for (int q = 0; q < 2; ++q) {        // 2 x 32 steps = TS
          if (sbc + 1 < nsb) {
#pragma unroll
            for (int i = 0; i < 8; ++i) nxt[i] = pr[(sbc + 1) * 8 + i];
          }
#pragma unroll
          for (int i = 0; i < 8; ++i) {
            const f4 p = buf[i];
            f4 a, r, c;
#pragma unroll
            for (int j = 0; j < 4; ++j) {
              float rF   = __builtin_amdgcn_rcpf(fmaxf(F, GA_EPS));
              float fcap = fmaxf(Kv + kpd * rF, GA_MIN_INF);
              float fact = fminf(p[j], fcap);
              r[j] = fmaxf(p[j] - fact, 0.0f);
              F += fact;
              a[j] = fact;
              c[j] = F;
            }
            const int t0 = q * 32 + i * 4;
            *reinterpret_cast<f4*>(L0 + t0) = a;
            *reinterpret_cast<f4*>(L1 + t0) = r;
            *reinterpret_cast<f4*>(L2 + t0) = c;
          }
#pragma unroll
          for (int i = 0; i < 8; ++i) buf[i] = nxt[i];
          ++sbc;
        }
      } else {
        sbc += 2;                             // keep loop-carried state uniform
      }
      // reconverged: one barrier per stage for the whole wave
      asm volatile("s_waitcnt lgkmcnt(0)" ::: "memory");
      __builtin_amdgcn_s_barrier();
    }
  } else {
    // ---------- consumers: 2 waves per stream (row halves), nt stores ------
    const int s = (wid - 1) % 3;             // stream
    const int h = (wid - 1) / 3;             // row half: rows h*16 .. h*16+15
    float* const dst = out + (size_t)s * BT;
    const int fr = lane >> 4;                // 0..3 : row within quad
    const int fc = (lane & 15) * 4;          // float col 0..60

    for (int st = 0; st < nstage; ++st) {
      if (st > 0) {
        const int tb = (st - 1) * TS;
        const float* const src = &sb[(st - 1) & 1][s][0];
#pragma unroll
        for (int g = 0; g < 4; ++g) {
          const int r = h * 16 + g * 4 + fr;
          f4 v = *reinterpret_cast<const f4*>(&src[r * PITCH + fc]);
          __builtin_nontemporal_store(
              v, reinterpret_cast<f4*>(dst + (size_t)(rowbase + r) * T + tb + fc));
        }
      }
      asm volatile("s_waitcnt lgkmcnt(0)" ::: "memory");
      __builtin_amdgcn_s_barrier();
    }
    // drain final stage (producer is done; no barrier needed)
    {
      const int tb = (nstage - 1) * TS;
      const float* const src = &sb[(nstage - 1) & 1][s][0];
#pragma unroll
      for (int g = 0; g < 4; ++g) {
        const int r = h * 16 + g * 4 + fr;
        f4 v = *reinterpret_cast<const f4*>(&src[r * PITCH + fc]);
        __builtin_nontemporal_store(
            v, reinterpret_cast<f4*>(dst + (size_t)(rowbase + r) * T + tb + fc));
      }
    }
  }
}

// Fallback for shapes not divisible by the tiling (not hit for 16384x2048).
__global__ void ga_fallback(
    const float* __restrict__ precip, const float* __restrict__ K,
    const float* __restrict__ psi, const float* __restrict__ dtheta,
    float* __restrict__ out, int B, int T) {
  int b = blockIdx.x * blockDim.x + threadIdx.x;
  if (b >= B) return;
  const float Kv  = K[b];
  const float kpd = Kv * (psi[b] * dtheta[b]);
  const size_t BT = (size_t)B * (size_t)T;
  float F = 0.0f;
  for (int t = 0; t < T; ++t) {
    float pv   = precip[(size_t)b * T + t];
    float rF   = __builtin_amdgcn_rcpf(fmaxf(F, GA_EPS));
    float fcap = fmaxf(Kv + kpd * rF, GA_MIN_INF);
    float fact = fminf(pv, fcap);
    float ro   = fmaxf(pv - fact, 0.0f);
    F += fact;
    out[(size_t)b * T + t] = fact;
    out[BT + (size_t)b * T + t] = ro;
    out[2 * BT + (size_t)b * T + t] = F;
  }
}

extern "C" void kernel_launch(void* const* d_in, const int* in_sizes, int n_in,
                              void* d_out, int out_size, void* d_ws, size_t ws_size,
                              hipStream_t stream) {
  const float* precip = (const float*)d_in[0];
  const float* K      = (const float*)d_in[1];
  const float* psi    = (const float*)d_in[2];
  const float* dtheta = (const float*)d_in[3];
  float* out = (float*)d_out;

  const int B = in_sizes[1];            // K has B elements
  const int T = in_sizes[0] / B;        // precip is B*T

  if ((B % ROWS) == 0 && (T % TS) == 0 && ((T / 32) % 2) == 0) {
    ga_pc<<<B / ROWS, 448, 0, stream>>>(precip, K, psi, dtheta, out, B, T);
  } else {
    ga_fallback<<<(B + 63) / 64, 64, 0, stream>>>(precip, K, psi, dtheta, out, B, T);
  }
}